// Round 12
// baseline (158.505 us; speedup 1.0000x reference)
//
#include <hip/hip_runtime.h>
#include <math.h>

// Capsule dynamic routing, B=64, R=4608, C=32, Din=Dout=16, 3 iters.
// b-logits are linear in v -> keep only vsum; u_hat recomputed per pass via
// mfma_f32_32x32x16_f16 (K=16==Din, A=Wfrag, B=xfrag -> D[(c,o)][b]).
//
// Round-12 (attributable wins only):
//  - caps_prep: LDS-transpose tile (8r x 64b). Old version was a 288KB-stride
//    lane scatter (64 txns/instr). Reads now 512B-contiguous per b, writes
//    coalesced 2KB/r.
//  - mfma geometry = round 8's measured-equal RB=36 / 1024thr / 1 N-tile per
//    wave -> 128 partials: reduce1 traffic halves (33.6 -> 16.8 MB).
//  - XCD-pairing swizzle: the two bh-blocks of a chunk (same wp slice) map to
//    the same XCD (D%8 == chunk%8), second one L2-hits.
//  - wprep unchanged from round 11 (four structures all ~80us, cause not
//    visible in capturable counters -- stop churning it blind).

#define B_    64
#define R_    4608
#define C_    32
#define RB    36
#define NBLK  (R_ / RB)      // 128
#define SELEM 32768          // 512 * 64

typedef _Float16 half8  __attribute__((ext_vector_type(8)));
typedef _Float16 half2v __attribute__((ext_vector_type(2)));
typedef float    f32x16 __attribute__((ext_vector_type(16)));

__device__ __forceinline__ void gload_lds16(const void* g, void* l) {
    __builtin_amdgcn_global_load_lds(
        (const __attribute__((address_space(1))) void*)g,
        (__attribute__((address_space(3))) void*)l, 16, 0, 0);
}

// ------------------------------------------------------------------ prep
// x [64][4608][16] f32 -> xa [4608][64][16] f16 via 8r x 64b LDS tile.
// Read: thread (b = t>>3, j8 = t&7) takes row (b, r0+j8) = 64B contiguous;
// lanes cover 8 x 512B segments (coalesced bursts). Write: thread (rl = t>>6,
// q = t&63) emits 32B at xa[r0+rl][q][:] -> 2KB contiguous per r.
__global__ __launch_bounds__(512)
void caps_prep(const float* __restrict__ x, _Float16* __restrict__ xa)
{
    __shared__ _Float16 tl[8][64][16];        // 16 KB
    const int t  = threadIdx.x;
    const int r0 = blockIdx.x * 8;

    {
        const int b = t >> 3, j8 = t & 7;
        const float4* xs = (const float4*)(x + ((size_t)b * R_ + r0 + j8) * 16);
        const float4 A = xs[0], Bv = xs[1], Cv = xs[2], Dv = xs[3];
        half8 lo, hi;
        lo[0]=(_Float16)A.x;  lo[1]=(_Float16)A.y;  lo[2]=(_Float16)A.z;  lo[3]=(_Float16)A.w;
        lo[4]=(_Float16)Bv.x; lo[5]=(_Float16)Bv.y; lo[6]=(_Float16)Bv.z; lo[7]=(_Float16)Bv.w;
        hi[0]=(_Float16)Cv.x; hi[1]=(_Float16)Cv.y; hi[2]=(_Float16)Cv.z; hi[3]=(_Float16)Cv.w;
        hi[4]=(_Float16)Dv.x; hi[5]=(_Float16)Dv.y; hi[6]=(_Float16)Dv.z; hi[7]=(_Float16)Dv.w;
        *(half8*)&tl[j8][b][0] = lo;
        *(half8*)&tl[j8][b][8] = hi;
    }
    __syncthreads();
    {
        const int rl = t >> 6, q = t & 63;
        _Float16* dst = xa + (size_t)(r0 + rl) * 1024 + q * 16;
        *(half8*)dst       = *(const half8*)&tl[rl][q][0];
        *(half8*)(dst + 8) = *(const half8*)&tl[rl][q][8];
    }
}

// ------------------------------------------------------------------ wprep
// (round-11, unchanged) LDS-free gather: wave-unit u = r*16+nt produces the
// 1KB wp row wp[u*512+lane*8+e] = (f16) W[r][2nt+(l31>>4)][8h+e][l31&15].
__global__ __launch_bounds__(512)
void caps_wprep(const float* __restrict__ W, _Float16* __restrict__ wp)
{
    const int wu   = (blockIdx.x * 512 + threadIdx.x) >> 6;
    const int lane = threadIdx.x & 63;
    const int h    = lane >> 5;
    const int l31  = lane & 31;
    const int cp   = l31 >> 4;
    const int o    = l31 & 15;

#pragma unroll
    for (int i = 0; i < 4; ++i) {
        const int u  = wu * 4 + i;                 // < 73728
        const int r  = u >> 4;
        const int nt = u & 15;
        const float* src = W + (((size_t)r * 32 + 2 * nt + cp) * 16 + 8 * h) * 16 + o;
        half8 f;
#pragma unroll
        for (int e = 0; e < 8; ++e)
            f[e] = (_Float16)src[e * 16];
        *(half8*)(wp + (size_t)u * 512 + lane * 8) = f;
    }
}

// ------------------------------------------------------------- MFMA pass
// (round-8 body) D = mfma(A=Wfrag, B=xfrag): D[row=(c,o)][col=b_loc].
// 1D grid 256 with XCD-pairing: xcd = D%8; s = D/8; chunk = (s>>1)*8 + xcd;
// bh = s&1  -> both bh of a chunk share an XCD (L2 hits on the wp slice).
template<bool FIRST>
__global__ __launch_bounds__(1024, 4)
void caps_mfma(const _Float16* __restrict__ xa, const _Float16* __restrict__ wp,
               const float* __restrict__ vsumT, float* __restrict__ sdst)
{
    __shared__ _Float16 xalds[RB * 512];      // 36 KB
    __shared__ float t_lds[32][33];
    __shared__ float c_lds[32][33];

    const int D     = blockIdx.x;
    const int xcd   = D & 7;
    const int slot  = D >> 3;
    const int chunk = (slot >> 1) * 8 + xcd;  // 0..127
    const int bh    = slot & 1;

    const int tid  = threadIdx.x;
    const int lane = tid & 63;
    const int wv   = tid >> 6;                // 0..15 = N-tile
    const int h    = lane >> 5;
    const int l31  = lane & 31;
    const int r0   = chunk * RB;
    const int bg   = bh * 32 + l31;

    // stage x tile (coalesced; involution swizzle validated round 6)
    {
        const int slx = (lane << 4) ^ (((lane >> 3) & 7) << 4);
        for (int t = wv; t < RB; t += 16) {
            const char* src = (const char*)xa + (size_t)(r0 + t) * 2048 + bh * 1024 + slx;
            gload_lds16(src, (char*)xalds + t * 1024);
        }
    }

    f32x16 sacc, zf;
#pragma unroll
    for (int k = 0; k < 16; ++k) { sacc[k] = 0.f; zf[k] = 0.f; }

    half2v vh[8];
    if (!FIRST) {
#pragma unroll
        for (int e = 0; e < 16; ++e) {
            const int g = wv * 32 + (e & 3) + 8 * (e >> 2) + 4 * h;
            vh[e >> 1][e & 1] = (_Float16)vsumT[(size_t)g * 64 + bg];
        }
    }

    asm volatile("s_waitcnt vmcnt(0)" ::: "memory");
    __syncthreads();

    const int avoff = ((l31 << 5) + (h << 4)) ^ (((l31 >> 2) & 7) << 4);

    const size_t wstride = 16 * 64 * 8;       // f16 per r
    half8 bc = *(const half8*)(wp + (((size_t)r0 * 16 + wv) * 64 + lane) * 8);

#pragma unroll 1
    for (int t = 0; t < RB; ++t) {
        const half8 av = *(const half8*)((const char*)xalds + t * 1024 + avoff);

        f32x16 u;
        if (FIRST) {
            sacc = __builtin_amdgcn_mfma_f32_32x32x16_f16(bc, av, sacc, 0, 0, 0);
        } else {
            u = __builtin_amdgcn_mfma_f32_32x32x16_f16(bc, av, zf, 0, 0, 0);
        }

        const int tn = (t < RB - 1) ? (t + 1) : t;
        bc = *(const half8*)(wp + ((size_t)(r0 + tn)) * wstride
                                + ((size_t)wv * 64 + lane) * 8);

        if (FIRST) continue;

        // logits: in-register o-reduce + one half-swap fold per capsule
        {
            float s0 = 0.f, s1 = 0.f;
#pragma unroll
            for (int e2 = 0; e2 < 4; ++e2) {
                s0 += u[2 * e2]         * (float)vh[e2][0];
                s0 += u[2 * e2 + 1]     * (float)vh[e2][1];
                s1 += u[8 + 2 * e2]     * (float)vh[4 + e2][0];
                s1 += u[8 + 2 * e2 + 1] * (float)vh[4 + e2][1];
            }
            s0 += __shfl_xor(s0, 32);
            s1 += __shfl_xor(s1, 32);
            if (h == 0) {
                t_lds[2 * wv    ][l31] = s0;
                t_lds[2 * wv + 1][l31] = s1;
            }
        }
        __syncthreads();

        // softmax over c: threads 0..511 -> (c-pair a_, local b2)
        if (tid < 512) {
            const int a_ = lane & 15;
            const int b2 = tid >> 4;
            const float tA = t_lds[2 * a_][b2];
            const float tB = t_lds[2 * a_ + 1][b2];
            float m = fmaxf(tA, tB);
            m = fmaxf(m, __shfl_xor(m, 1));
            m = fmaxf(m, __shfl_xor(m, 2));
            m = fmaxf(m, __shfl_xor(m, 4));
            m = fmaxf(m, __shfl_xor(m, 8));
            const float eA = __expf(tA - m);
            const float eB = __expf(tB - m);
            float zs = eA + eB;
            zs += __shfl_xor(zs, 1);
            zs += __shfl_xor(zs, 2);
            zs += __shfl_xor(zs, 4);
            zs += __shfl_xor(zs, 8);
            const float inv = 1.0f / zs;
            c_lds[2 * a_][b2]     = eA * inv;
            c_lds[2 * a_ + 1][b2] = eB * inv;
        }
        __syncthreads();

        // accumulate: sacc += c_ij * u
        {
            const float c0v = c_lds[2 * wv    ][l31];
            const float c1v = c_lds[2 * wv + 1][l31];
#pragma unroll
            for (int e = 0; e < 8; ++e)  sacc[e] += c0v * u[e];
#pragma unroll
            for (int e = 8; e < 16; ++e) sacc[e] += c1v * u[e];
        }
    }

    // epilogue: transposed partial store sT[g][b] (coalesced over b)
    const float scale = FIRST ? 0.03125f : 1.0f;
    float* sp = sdst + ((size_t)chunk << 15);
#pragma unroll
    for (int e = 0; e < 16; ++e) {
        const int g = wv * 32 + (e & 3) + 8 * (e >> 2) + 4 * h;
        sp[(size_t)g * 64 + bg] = sacc[e] * scale;
    }
}

// ------------------------------------------------- reductions + squash
// stage 1: 128 partials -> 8 (elementwise)
__global__ __launch_bounds__(256)
void caps_reduce1(const float* __restrict__ sp, float* __restrict__ s2)
{
    const int e  = blockIdx.x * 256 + threadIdx.x;
    const int pg = blockIdx.y;
    const float* p0 = sp + (size_t)pg * 16 * SELEM + e;
    float a = 0.0f;
#pragma unroll 8
    for (int p = 0; p < 16; ++p) a += p0[(size_t)p * SELEM];
    s2[pg * SELEM + e] = a;
}

// stage 2: thread owns (c,b), o in registers -> shuffle-free squash.
// mode 0: vsumT = v; 1: vsumT += v; 2: out[b][c][o] = v.
__global__ __launch_bounds__(64)
void caps_reduce2T(const float* __restrict__ src, float* __restrict__ vsumT,
                   float* __restrict__ out, int mode)
{
    const int c = blockIdx.x;
    const int b = threadIdx.x;
    float a[16];
#pragma unroll
    for (int o = 0; o < 16; ++o) a[o] = 0.0f;
    for (int p = 0; p < 8; ++p)
#pragma unroll
        for (int o = 0; o < 16; ++o)
            a[o] += src[(size_t)p * SELEM + c * 1024 + o * 64 + b];
    float sq = 0.0f;
#pragma unroll
    for (int o = 0; o < 16; ++o) sq += a[o] * a[o];
    const float n  = sqrtf(sq);
    const float sc = sq / (1.0f + sq) / (n + 1e-8f);
    if (mode == 2) {
#pragma unroll
        for (int o = 0; o < 16; ++o)
            out[(size_t)b * 512 + c * 16 + o] = a[o] * sc;
    } else if (mode == 0) {
#pragma unroll
        for (int o = 0; o < 16; ++o)
            vsumT[c * 1024 + o * 64 + b] = a[o] * sc;
    } else {
#pragma unroll
        for (int o = 0; o < 16; ++o)
            vsumT[c * 1024 + o * 64 + b] += a[o] * sc;
    }
}

// old-layout reduce2 (tier-3 fallback only)
__global__ __launch_bounds__(256)
void caps_reduce2(const float* __restrict__ src, int P,
                  float* __restrict__ vsum, float* __restrict__ out, int mode)
{
    const int e = blockIdx.x * 256 + threadIdx.x;
    float a = 0.0f;
    for (int p = 0; p < P; ++p) a += src[(size_t)p * SELEM + e];
    float sq = a * a;
#pragma unroll
    for (int off = 8; off >= 1; off >>= 1) sq += __shfl_xor(sq, off);
    const float n = sqrtf(sq);
    const float v = a * (sq / (1.0f + sq) / (n + 1e-8f));
    if (mode == 0)      vsum[e] = v;
    else if (mode == 1) vsum[e] += v;
    else                out[e] = v;
}

// ------------------------------------- tier-3 fallback: fp32 VALU path
template<bool FIRST>
__global__ __launch_bounds__(1024, 4)
void caps_pass_f32(const float* __restrict__ x, const float* __restrict__ W,
                   const float* __restrict__ vsumg, float* __restrict__ sdst)
{
    __shared__ float wlds[2][8192];
    const int tid = threadIdx.x, lane = tid & 63;
    const int c = tid & 31, dh = (tid >> 5) & 1, w = tid >> 6;
    const int r0 = blockIdx.x * RB, b0 = w << 2;
    const int key = (c & 7) << 4;
    const int cb  = (c << 10) + (dh << 5);

    float sacc[4][8];
#pragma unroll
    for (int q = 0; q < 4; ++q)
#pragma unroll
        for (int k = 0; k < 8; ++k) sacc[q][k] = 0.0f;

    float vreg[4][8];
    if (!FIRST) {
#pragma unroll
        for (int q = 0; q < 4; ++q) {
            const float4* vp = (const float4*)(vsumg + ((((b0+q) << 5) + c) << 4) + (dh << 3));
            float4 a = vp[0], bq = vp[1];
            vreg[q][0]=a.x; vreg[q][1]=a.y; vreg[q][2]=a.z; vreg[q][3]=a.w;
            vreg[q][4]=bq.x; vreg[q][5]=bq.y; vreg[q][6]=bq.z; vreg[q][7]=bq.w;
        }
    }

    const int Dloc0 = (w << 11);
    const int lx0 = (lane << 4) ^ ((((w << 1))     & 7) << 4);
    const int lx1 = (lane << 4) ^ ((((w << 1) | 1) & 7) << 4);
    const int wu = __builtin_amdgcn_readfirstlane(w);
    const float* xw = x + (size_t)((wu << 2) * R_ + r0) * 16;

#define STAGE(buf, r)                                                              \
    do {                                                                           \
        const char* wr_ = (const char*)W + ((size_t)(r) << 15);                    \
        gload_lds16(wr_ + Dloc0        + lx0, (char*)wlds[buf] + Dloc0);           \
        gload_lds16(wr_ + Dloc0 + 1024 + lx1, (char*)wlds[buf] + Dloc0 + 1024);    \
    } while (0)

    STAGE(0, r0);
#pragma unroll 1
    for (int t = 0; t < RB; ++t) {
        const int cur = t & 1;
        if (t + 1 < RB) { STAGE(cur ^ 1, r0 + t + 1); asm volatile("s_waitcnt vmcnt(2)" ::: "memory"); }
        else            { asm volatile("s_waitcnt vmcnt(0)" ::: "memory"); }
        __builtin_amdgcn_s_barrier();
        __builtin_amdgcn_sched_barrier(0);

        const char* lb = (const char*)wlds[cur];
        float u[4][8];
#pragma unroll
        for (int q = 0; q < 4; ++q)
#pragma unroll
            for (int k = 0; k < 8; ++k) u[q][k] = 0.0f;

#pragma unroll
        for (int i = 0; i < 16; ++i) {
            const int A = (cb + (i << 6)) ^ key;
            float4 w0 = *(const float4*)(lb + A);
            float4 w1 = *(const float4*)(lb + (A ^ 16));
            float wv[8] = {w0.x, w0.y, w0.z, w0.w, w1.x, w1.y, w1.z, w1.w};
#pragma unroll
            for (int q = 0; q < 4; ++q) {
                const float xv = xw[(size_t)q * (R_ * 16) + t * 16 + i];
#pragma unroll
                for (int k = 0; k < 8; ++k) u[q][k] = fmaf(xv, wv[k], u[q][k]);
            }
        }

#pragma unroll
        for (int q = 0; q < 4; ++q) {
            float cij;
            if (FIRST) cij = 0.03125f;
            else {
                float th = 0.0f;
#pragma unroll
                for (int k = 0; k < 8; ++k) th = fmaf(u[q][k], vreg[q][k], th);
                th += __shfl_xor(th, 32);
                float m = th;
#pragma unroll
                for (int off = 16; off >= 1; off >>= 1) m = fmaxf(m, __shfl_xor(m, off));
                const float e = __expf(th - m);
                float ssum = e;
#pragma unroll
                for (int off = 16; off >= 1; off >>= 1) ssum += __shfl_xor(ssum, off);
                cij = e / ssum;
            }
#pragma unroll
            for (int k = 0; k < 8; ++k) sacc[q][k] = fmaf(cij, u[q][k], sacc[q][k]);
        }
        __builtin_amdgcn_s_barrier();
    }
#undef STAGE

#pragma unroll
    for (int q = 0; q < 4; ++q) {
        float* sp = sdst + ((((b0+q) << 5) + c) << 4) + (dh << 3);
#pragma unroll
        for (int k = 0; k < 8; ++k) atomicAdd(sp + k, sacc[q][k]);
    }
}

// ---------------------------------------------------------------- launcher
extern "C" void kernel_launch(void* const* d_in, const int* in_sizes, int n_in,
                              void* d_out, int out_size, void* d_ws, size_t ws_size,
                              hipStream_t stream)
{
    const float* x = (const float*)d_in[0];          // [64, 4608, 16]
    const float* W = (const float*)d_in[1];          // [4608, 32, 16, 16]
    float* out = (float*)d_out;                      // [64, 32, 16]

    const size_t WPB = (size_t)R_ * 16 * 64 * 8 * sizeof(_Float16);  // 75,497,472
    const size_t XAB = (size_t)R_ * 64 * 16 * sizeof(_Float16);      //  9,437,184
    const size_t SPB = (size_t)NBLK * SELEM * sizeof(float);         // 16,777,216
    const size_t S2B = (size_t)8 * SELEM * sizeof(float);
    const size_t VSB = (size_t)SELEM * sizeof(float);
    char* wsc = (char*)d_ws;

    if (ws_size >= WPB + XAB + SPB + S2B + VSB) {
        _Float16* wp  = (_Float16*)wsc;
        _Float16* xa  = (_Float16*)(wsc + WPB);
        float* s_part = (float*)(wsc + WPB + XAB);
        float* s2     = (float*)(wsc + WPB + XAB + SPB);
        float* vsumT  = (float*)(wsc + WPB + XAB + SPB + S2B);

        caps_prep<<<576, 512, 0, stream>>>(x, xa);
        caps_wprep<<<2304, 512, 0, stream>>>(W, wp);

        caps_mfma<true ><<<256, 1024, 0, stream>>>(xa, wp, nullptr, s_part);
        caps_reduce1<<<dim3(128, 8), 256, 0, stream>>>(s_part, s2);
        caps_reduce2T<<<32, 64, 0, stream>>>(s2, vsumT, nullptr, 0);

        caps_mfma<false><<<256, 1024, 0, stream>>>(xa, wp, vsumT, s_part);
        caps_reduce1<<<dim3(128, 8), 256, 0, stream>>>(s_part, s2);
        caps_reduce2T<<<32, 64, 0, stream>>>(s2, vsumT, nullptr, 1);

        caps_mfma<false><<<256, 1024, 0, stream>>>(xa, wp, vsumT, s_part);
        caps_reduce1<<<dim3(128, 8), 256, 0, stream>>>(s_part, s2);
        caps_reduce2T<<<32, 64, 0, stream>>>(s2, vsumT, out, 2);
    } else {
        // tiny-ws fallback: fp32 VALU path (atomic accumulate, old layout)
        float* s    = (float*)wsc;
        float* vsum = s + SELEM;

        hipMemsetAsync(s, 0, VSB, stream);
        caps_pass_f32<true><<<NBLK, 1024, 0, stream>>>(x, W, nullptr, s);
        caps_reduce2<<<128, 256, 0, stream>>>(s, 1, vsum, nullptr, 0);

        hipMemsetAsync(s, 0, VSB, stream);
        caps_pass_f32<false><<<NBLK, 1024, 0, stream>>>(x, W, vsum, s);
        caps_reduce2<<<128, 256, 0, stream>>>(s, 1, vsum, nullptr, 1);

        hipMemsetAsync(s, 0, VSB, stream);
        caps_pass_f32<false><<<NBLK, 1024, 0, stream>>>(x, W, vsum, s);
        caps_reduce2<<<128, 256, 0, stream>>>(s, 1, nullptr, out, 2);
    }
}

// Round 13
// 156.301 us; speedup vs baseline: 1.0141x; 1.0141x over previous
//
#include <hip/hip_runtime.h>
#include <math.h>

// Capsule dynamic routing, B=64, R=4608, C=32, Din=Dout=16, 3 iters.
// b-logits are linear in v -> keep only vsum; u_hat recomputed per pass via
// mfma_f32_32x32x16_f16 (K=16==Din, A=Wfrag, B=xfrag -> D[(c,o)][b]).
//
// Round-13: kill the standalone W-conversion kernel (5 structures all pinned
// ~80-85us with every capturable counter idle). Pass 1 (FIRST) now fuses the
// fragment gather: per r, each wave loads its 8 f32 W elements (stride-64B,
// lines fully consumed), converts, MFMAs, and stores the half8 fragment to
// wp (bh==0 blocks only). FIRST's loop has no barriers, so the r+1 gather
// pipelines under r's MFMA. Passes 2-3 read wp unchanged (round-8 body).

#define B_    64
#define R_    4608
#define C_    32
#define RB    36
#define NBLK  (R_ / RB)      // 128
#define SELEM 32768          // 512 * 64

typedef _Float16 half8  __attribute__((ext_vector_type(8)));
typedef _Float16 half2v __attribute__((ext_vector_type(2)));
typedef float    f32x16 __attribute__((ext_vector_type(16)));

__device__ __forceinline__ void gload_lds16(const void* g, void* l) {
    __builtin_amdgcn_global_load_lds(
        (const __attribute__((address_space(1))) void*)g,
        (__attribute__((address_space(3))) void*)l, 16, 0, 0);
}

// ------------------------------------------------------------------ prep
// x [64][4608][16] f32 -> xa [4608][64][16] f16 via 8r x 64b LDS tile.
__global__ __launch_bounds__(512)
void caps_prep(const float* __restrict__ x, _Float16* __restrict__ xa)
{
    __shared__ _Float16 tl[8][64][16];        // 16 KB
    const int t  = threadIdx.x;
    const int r0 = blockIdx.x * 8;

    {
        const int b = t >> 3, j8 = t & 7;
        const float4* xs = (const float4*)(x + ((size_t)b * R_ + r0 + j8) * 16);
        const float4 A = xs[0], Bv = xs[1], Cv = xs[2], Dv = xs[3];
        half8 lo, hi;
        lo[0]=(_Float16)A.x;  lo[1]=(_Float16)A.y;  lo[2]=(_Float16)A.z;  lo[3]=(_Float16)A.w;
        lo[4]=(_Float16)Bv.x; lo[5]=(_Float16)Bv.y; lo[6]=(_Float16)Bv.z; lo[7]=(_Float16)Bv.w;
        hi[0]=(_Float16)Cv.x; hi[1]=(_Float16)Cv.y; hi[2]=(_Float16)Cv.z; hi[3]=(_Float16)Cv.w;
        hi[4]=(_Float16)Dv.x; hi[5]=(_Float16)Dv.y; hi[6]=(_Float16)Dv.z; hi[7]=(_Float16)Dv.w;
        *(half8*)&tl[j8][b][0] = lo;
        *(half8*)&tl[j8][b][8] = hi;
    }
    __syncthreads();
    {
        const int rl = t >> 6, q = t & 63;
        _Float16* dst = xa + (size_t)(r0 + rl) * 1024 + q * 16;
        *(half8*)dst       = *(const half8*)&tl[rl][q][0];
        *(half8*)(dst + 8) = *(const half8*)&tl[rl][q][8];
    }
}

// ------------------------------------------------------------- MFMA pass
// D = mfma(A=Wfrag, B=xfrag): D[row=(c,o)][col=b_loc].
// lane: col b_loc = lane&31; rows (regs): R(e,h) = (e&3)+8*(e>>2)+4*h.
// wave wv owns N-tile wv: c = 2*wv+(l31>>4), o = l31&15, k = 8h+e.
// XCD-pairing: xcd = D%8; s = D/8; chunk = (s>>1)*8+xcd; bh = s&1.
// FIRST: gathers W f32 in fragment order per r (8 loads, no in-loop
// barriers -> deep pipelining), converts, MFMAs, stores frag to wp (bh==0).
// Non-FIRST: reads wp (validated round-8 body, unchanged).
template<bool FIRST>
__global__ __launch_bounds__(1024, 4)
void caps_mfma(const _Float16* __restrict__ xa, const float* __restrict__ Wg,
               _Float16* __restrict__ wp, const float* __restrict__ vsumT,
               float* __restrict__ sdst)
{
    __shared__ _Float16 xalds[RB * 512];      // 36 KB
    __shared__ float t_lds[32][33];
    __shared__ float c_lds[32][33];

    const int D     = blockIdx.x;
    const int xcd   = D & 7;
    const int slot  = D >> 3;
    const int chunk = (slot >> 1) * 8 + xcd;  // 0..127
    const int bh    = slot & 1;

    const int tid  = threadIdx.x;
    const int lane = tid & 63;
    const int wv   = tid >> 6;                // 0..15 = N-tile
    const int h    = lane >> 5;
    const int l31  = lane & 31;
    const int r0   = chunk * RB;
    const int bg   = bh * 32 + l31;

    // stage x tile (coalesced; involution swizzle validated round 6)
    {
        const int slx = (lane << 4) ^ (((lane >> 3) & 7) << 4);
        for (int t = wv; t < RB; t += 16) {
            const char* src = (const char*)xa + (size_t)(r0 + t) * 2048 + bh * 1024 + slx;
            gload_lds16(src, (char*)xalds + t * 1024);
        }
    }

    f32x16 sacc, zf;
#pragma unroll
    for (int k = 0; k < 16; ++k) { sacc[k] = 0.f; zf[k] = 0.f; }

    half2v vh[8];
    if (!FIRST) {
#pragma unroll
        for (int e = 0; e < 16; ++e) {
            const int g = wv * 32 + (e & 3) + 8 * (e >> 2) + 4 * h;
            vh[e >> 1][e & 1] = (_Float16)vsumT[(size_t)g * 64 + bg];
        }
    }

    asm volatile("s_waitcnt vmcnt(0)" ::: "memory");
    __syncthreads();

    const int avoff = ((l31 << 5) + (h << 4)) ^ (((l31 >> 2) & 7) << 4);

    // W-fragment addressing (identical indices to the validated wprep)
    const int c_ = 2 * wv + (l31 >> 4);
    const int o_ = l31 & 15;
#define WGATHER(dst, r)                                                           \
    do {                                                                          \
        const float* ws_ = Wg + (((size_t)(r) * 32 + c_) * 16 + 8 * h) * 16 + o_; \
        _Pragma("unroll")                                                         \
        for (int e_ = 0; e_ < 8; ++e_) dst[e_] = (_Float16)ws_[e_ * 16];          \
    } while (0)

    const size_t wstride = 16 * 64 * 8;       // f16 per r
    half8 bc;
    if (FIRST) {
        WGATHER(bc, r0);
    } else {
        bc = *(const half8*)(wp + (((size_t)r0 * 16 + wv) * 64 + lane) * 8);
    }

#pragma unroll 1
    for (int t = 0; t < RB; ++t) {
        const half8 av = *(const half8*)((const char*)xalds + t * 1024 + avoff);

        if (FIRST) {
            sacc = __builtin_amdgcn_mfma_f32_32x32x16_f16(bc, av, sacc, 0, 0, 0);
            if (bh == 0)
                *(half8*)(wp + (((size_t)(r0 + t) * 16 + wv) * 64 + lane) * 8) = bc;
            if (t + 1 < RB) WGATHER(bc, r0 + t + 1);
            continue;
        }

        f32x16 u = __builtin_amdgcn_mfma_f32_32x32x16_f16(bc, av, zf, 0, 0, 0);

        const int tn = (t < RB - 1) ? (t + 1) : t;
        bc = *(const half8*)(wp + ((size_t)(r0 + tn)) * wstride
                                + ((size_t)wv * 64 + lane) * 8);

        // logits: in-register o-reduce + one half-swap fold per capsule
        {
            float s0 = 0.f, s1 = 0.f;
#pragma unroll
            for (int e2 = 0; e2 < 4; ++e2) {
                s0 += u[2 * e2]         * (float)vh[e2][0];
                s0 += u[2 * e2 + 1]     * (float)vh[e2][1];
                s1 += u[8 + 2 * e2]     * (float)vh[4 + e2][0];
                s1 += u[8 + 2 * e2 + 1] * (float)vh[4 + e2][1];
            }
            s0 += __shfl_xor(s0, 32);
            s1 += __shfl_xor(s1, 32);
            if (h == 0) {
                t_lds[2 * wv    ][l31] = s0;
                t_lds[2 * wv + 1][l31] = s1;
            }
        }
        __syncthreads();

        // softmax over c: threads 0..511 -> (c-pair a_, local b2)
        if (tid < 512) {
            const int a_ = lane & 15;
            const int b2 = tid >> 4;
            const float tA = t_lds[2 * a_][b2];
            const float tB = t_lds[2 * a_ + 1][b2];
            float m = fmaxf(tA, tB);
            m = fmaxf(m, __shfl_xor(m, 1));
            m = fmaxf(m, __shfl_xor(m, 2));
            m = fmaxf(m, __shfl_xor(m, 4));
            m = fmaxf(m, __shfl_xor(m, 8));
            const float eA = __expf(tA - m);
            const float eB = __expf(tB - m);
            float zs = eA + eB;
            zs += __shfl_xor(zs, 1);
            zs += __shfl_xor(zs, 2);
            zs += __shfl_xor(zs, 4);
            zs += __shfl_xor(zs, 8);
            const float inv = 1.0f / zs;
            c_lds[2 * a_][b2]     = eA * inv;
            c_lds[2 * a_ + 1][b2] = eB * inv;
        }
        __syncthreads();

        // accumulate: sacc += c_ij * u
        {
            const float c0v = c_lds[2 * wv    ][l31];
            const float c1v = c_lds[2 * wv + 1][l31];
#pragma unroll
            for (int e = 0; e < 8; ++e)  sacc[e] += c0v * u[e];
#pragma unroll
            for (int e = 8; e < 16; ++e) sacc[e] += c1v * u[e];
        }
    }
#undef WGATHER

    // epilogue: transposed partial store sT[g][b] (coalesced over b)
    const float scale = FIRST ? 0.03125f : 1.0f;
    float* sp = sdst + ((size_t)chunk << 15);
#pragma unroll
    for (int e = 0; e < 16; ++e) {
        const int g = wv * 32 + (e & 3) + 8 * (e >> 2) + 4 * h;
        sp[(size_t)g * 64 + bg] = sacc[e] * scale;
    }
}

// ------------------------------------------------- reductions + squash
// stage 1: 128 partials -> 8 (elementwise)
__global__ __launch_bounds__(256)
void caps_reduce1(const float* __restrict__ sp, float* __restrict__ s2)
{
    const int e  = blockIdx.x * 256 + threadIdx.x;
    const int pg = blockIdx.y;
    const float* p0 = sp + (size_t)pg * 16 * SELEM + e;
    float a = 0.0f;
#pragma unroll 8
    for (int p = 0; p < 16; ++p) a += p0[(size_t)p * SELEM];
    s2[pg * SELEM + e] = a;
}

// stage 2: thread owns (c,b), o in registers -> shuffle-free squash.
// mode 0: vsumT = v; 1: vsumT += v; 2: out[b][c][o] = v.
__global__ __launch_bounds__(64)
void caps_reduce2T(const float* __restrict__ src, float* __restrict__ vsumT,
                   float* __restrict__ out, int mode)
{
    const int c = blockIdx.x;
    const int b = threadIdx.x;
    float a[16];
#pragma unroll
    for (int o = 0; o < 16; ++o) a[o] = 0.0f;
    for (int p = 0; p < 8; ++p)
#pragma unroll
        for (int o = 0; o < 16; ++o)
            a[o] += src[(size_t)p * SELEM + c * 1024 + o * 64 + b];
    float sq = 0.0f;
#pragma unroll
    for (int o = 0; o < 16; ++o) sq += a[o] * a[o];
    const float n  = sqrtf(sq);
    const float sc = sq / (1.0f + sq) / (n + 1e-8f);
    if (mode == 2) {
#pragma unroll
        for (int o = 0; o < 16; ++o)
            out[(size_t)b * 512 + c * 16 + o] = a[o] * sc;
    } else if (mode == 0) {
#pragma unroll
        for (int o = 0; o < 16; ++o)
            vsumT[c * 1024 + o * 64 + b] = a[o] * sc;
    } else {
#pragma unroll
        for (int o = 0; o < 16; ++o)
            vsumT[c * 1024 + o * 64 + b] += a[o] * sc;
    }
}

// old-layout reduce2 (tier-3 fallback only)
__global__ __launch_bounds__(256)
void caps_reduce2(const float* __restrict__ src, int P,
                  float* __restrict__ vsum, float* __restrict__ out, int mode)
{
    const int e = blockIdx.x * 256 + threadIdx.x;
    float a = 0.0f;
    for (int p = 0; p < P; ++p) a += src[(size_t)p * SELEM + e];
    float sq = a * a;
#pragma unroll
    for (int off = 8; off >= 1; off >>= 1) sq += __shfl_xor(sq, off);
    const float n = sqrtf(sq);
    const float v = a * (sq / (1.0f + sq) / (n + 1e-8f));
    if (mode == 0)      vsum[e] = v;
    else if (mode == 1) vsum[e] += v;
    else                out[e] = v;
}

// ------------------------------------- tier-3 fallback: fp32 VALU path
template<bool FIRST>
__global__ __launch_bounds__(1024, 4)
void caps_pass_f32(const float* __restrict__ x, const float* __restrict__ W,
                   const float* __restrict__ vsumg, float* __restrict__ sdst)
{
    __shared__ float wlds[2][8192];
    const int tid = threadIdx.x, lane = tid & 63;
    const int c = tid & 31, dh = (tid >> 5) & 1, w = tid >> 6;
    const int r0 = blockIdx.x * RB, b0 = w << 2;
    const int key = (c & 7) << 4;
    const int cb  = (c << 10) + (dh << 5);

    float sacc[4][8];
#pragma unroll
    for (int q = 0; q < 4; ++q)
#pragma unroll
        for (int k = 0; k < 8; ++k) sacc[q][k] = 0.0f;

    float vreg[4][8];
    if (!FIRST) {
#pragma unroll
        for (int q = 0; q < 4; ++q) {
            const float4* vp = (const float4*)(vsumg + ((((b0+q) << 5) + c) << 4) + (dh << 3));
            float4 a = vp[0], bq = vp[1];
            vreg[q][0]=a.x; vreg[q][1]=a.y; vreg[q][2]=a.z; vreg[q][3]=a.w;
            vreg[q][4]=bq.x; vreg[q][5]=bq.y; vreg[q][6]=bq.z; vreg[q][7]=bq.w;
        }
    }

    const int Dloc0 = (w << 11);
    const int lx0 = (lane << 4) ^ ((((w << 1))     & 7) << 4);
    const int lx1 = (lane << 4) ^ ((((w << 1) | 1) & 7) << 4);
    const int wu = __builtin_amdgcn_readfirstlane(w);
    const float* xw = x + (size_t)((wu << 2) * R_ + r0) * 16;

#define STAGE(buf, r)                                                              \
    do {                                                                           \
        const char* wr_ = (const char*)W + ((size_t)(r) << 15);                    \
        gload_lds16(wr_ + Dloc0        + lx0, (char*)wlds[buf] + Dloc0);           \
        gload_lds16(wr_ + Dloc0 + 1024 + lx1, (char*)wlds[buf] + Dloc0 + 1024);    \
    } while (0)

    STAGE(0, r0);
#pragma unroll 1
    for (int t = 0; t < RB; ++t) {
        const int cur = t & 1;
        if (t + 1 < RB) { STAGE(cur ^ 1, r0 + t + 1); asm volatile("s_waitcnt vmcnt(2)" ::: "memory"); }
        else            { asm volatile("s_waitcnt vmcnt(0)" ::: "memory"); }
        __builtin_amdgcn_s_barrier();
        __builtin_amdgcn_sched_barrier(0);

        const char* lb = (const char*)wlds[cur];
        float u[4][8];
#pragma unroll
        for (int q = 0; q < 4; ++q)
#pragma unroll
            for (int k = 0; k < 8; ++k) u[q][k] = 0.0f;

#pragma unroll
        for (int i = 0; i < 16; ++i) {
            const int A = (cb + (i << 6)) ^ key;
            float4 w0 = *(const float4*)(lb + A);
            float4 w1 = *(const float4*)(lb + (A ^ 16));
            float wv[8] = {w0.x, w0.y, w0.z, w0.w, w1.x, w1.y, w1.z, w1.w};
#pragma unroll
            for (int q = 0; q < 4; ++q) {
                const float xv = xw[(size_t)q * (R_ * 16) + t * 16 + i];
#pragma unroll
                for (int k = 0; k < 8; ++k) u[q][k] = fmaf(xv, wv[k], u[q][k]);
            }
        }

#pragma unroll
        for (int q = 0; q < 4; ++q) {
            float cij;
            if (FIRST) cij = 0.03125f;
            else {
                float th = 0.0f;
#pragma unroll
                for (int k = 0; k < 8; ++k) th = fmaf(u[q][k], vreg[q][k], th);
                th += __shfl_xor(th, 32);
                float m = th;
#pragma unroll
                for (int off = 16; off >= 1; off >>= 1) m = fmaxf(m, __shfl_xor(m, off));
                const float e = __expf(th - m);
                float ssum = e;
#pragma unroll
                for (int off = 16; off >= 1; off >>= 1) ssum += __shfl_xor(ssum, off);
                cij = e / ssum;
            }
#pragma unroll
            for (int k = 0; k < 8; ++k) sacc[q][k] = fmaf(cij, u[q][k], sacc[q][k]);
        }
        __builtin_amdgcn_s_barrier();
    }
#undef STAGE

#pragma unroll
    for (int q = 0; q < 4; ++q) {
        float* sp = sdst + ((((b0+q) << 5) + c) << 4) + (dh << 3);
#pragma unroll
        for (int k = 0; k < 8; ++k) atomicAdd(sp + k, sacc[q][k]);
    }
}

// ---------------------------------------------------------------- launcher
extern "C" void kernel_launch(void* const* d_in, const int* in_sizes, int n_in,
                              void* d_out, int out_size, void* d_ws, size_t ws_size,
                              hipStream_t stream)
{
    const float* x = (const float*)d_in[0];          // [64, 4608, 16]
    const float* W = (const float*)d_in[1];          // [4608, 32, 16, 16]
    float* out = (float*)d_out;                      // [64, 32, 16]

    const size_t WPB = (size_t)R_ * 16 * 64 * 8 * sizeof(_Float16);  // 75,497,472
    const size_t XAB = (size_t)R_ * 64 * 16 * sizeof(_Float16);      //  9,437,184
    const size_t SPB = (size_t)NBLK * SELEM * sizeof(float);         // 16,777,216
    const size_t S2B = (size_t)8 * SELEM * sizeof(float);
    const size_t VSB = (size_t)SELEM * sizeof(float);
    char* wsc = (char*)d_ws;

    if (ws_size >= WPB + XAB + SPB + S2B + VSB) {
        _Float16* wp  = (_Float16*)wsc;
        _Float16* xa  = (_Float16*)(wsc + WPB);
        float* s_part = (float*)(wsc + WPB + XAB);
        float* s2     = (float*)(wsc + WPB + XAB + SPB);
        float* vsumT  = (float*)(wsc + WPB + XAB + SPB + S2B);

        caps_prep<<<576, 512, 0, stream>>>(x, xa);

        caps_mfma<true ><<<256, 1024, 0, stream>>>(xa, W, wp, nullptr, s_part);
        caps_reduce1<<<dim3(128, 8), 256, 0, stream>>>(s_part, s2);
        caps_reduce2T<<<32, 64, 0, stream>>>(s2, vsumT, nullptr, 0);

        caps_mfma<false><<<256, 1024, 0, stream>>>(xa, W, wp, vsumT, s_part);
        caps_reduce1<<<dim3(128, 8), 256, 0, stream>>>(s_part, s2);
        caps_reduce2T<<<32, 64, 0, stream>>>(s2, vsumT, nullptr, 1);

        caps_mfma<false><<<256, 1024, 0, stream>>>(xa, W, wp, vsumT, s_part);
        caps_reduce1<<<dim3(128, 8), 256, 0, stream>>>(s_part, s2);
        caps_reduce2T<<<32, 64, 0, stream>>>(s2, vsumT, out, 2);
    } else {
        // tiny-ws fallback: fp32 VALU path (atomic accumulate, old layout)
        float* s    = (float*)wsc;
        float* vsum = s + SELEM;

        hipMemsetAsync(s, 0, VSB, stream);
        caps_pass_f32<true><<<NBLK, 1024, 0, stream>>>(x, W, nullptr, s);
        caps_reduce2<<<128, 256, 0, stream>>>(s, 1, vsum, nullptr, 0);

        hipMemsetAsync(s, 0, VSB, stream);
        caps_pass_f32<false><<<NBLK, 1024, 0, stream>>>(x, W, vsum, s);
        caps_reduce2<<<128, 256, 0, stream>>>(s, 1, vsum, nullptr, 1);

        hipMemsetAsync(s, 0, VSB, stream);
        caps_pass_f32<false><<<NBLK, 1024, 0, stream>>>(x, W, vsum, s);
        caps_reduce2<<<128, 256, 0, stream>>>(s, 1, nullptr, out, 2);
    }
}

// Round 14
// 139.638 us; speedup vs baseline: 1.1351x; 1.1193x over previous
//
#include <hip/hip_runtime.h>
#include <math.h>

// Capsule dynamic routing, B=64, R=4608, C=32, Din=Dout=16, 3 iters.
// b-logits are linear in v -> keep only vsum; u_hat recomputed per pass via
// mfma_f32_32x32x16_f16 (K=16==Din, A=Wfrag, B=xfrag -> D[(c,o)][b]).
//
// Round-14: totals-only budget re-derivation (rocprof per-dispatch durations
// proven inflated in r2: 3x148 > 383 total) shows the 3 MFMA passes are
// ~35-40us each (~110 of 156), dominated by per-r barrier convoy (72 full-CU
// barriers/pass at 1 block/CU) + dependent logit/softmax phases -- NOT
// memory. Change: batch 2 r per iteration -> 2 MFMAs, one fused logit phase
// (2x ILP), softmax on all 1024 threads (was 512), one accumulate; barriers
// halve (72 -> 36). Softmax now in-place in t_lds (per-entry 1:1 thread map,
// wave-local across iters -> race-free). Everything else = round 13.

#define B_    64
#define R_    4608
#define C_    32
#define RB    36
#define NBLK  (R_ / RB)      // 128
#define SELEM 32768          // 512 * 64

typedef _Float16 half8  __attribute__((ext_vector_type(8)));
typedef _Float16 half2v __attribute__((ext_vector_type(2)));
typedef float    f32x16 __attribute__((ext_vector_type(16)));

__device__ __forceinline__ void gload_lds16(const void* g, void* l) {
    __builtin_amdgcn_global_load_lds(
        (const __attribute__((address_space(1))) void*)g,
        (__attribute__((address_space(3))) void*)l, 16, 0, 0);
}

// ------------------------------------------------------------------ prep
// x [64][4608][16] f32 -> xa [4608][64][16] f16 via 8r x 64b LDS tile.
__global__ __launch_bounds__(512)
void caps_prep(const float* __restrict__ x, _Float16* __restrict__ xa)
{
    __shared__ _Float16 tl[8][64][16];        // 16 KB
    const int t  = threadIdx.x;
    const int r0 = blockIdx.x * 8;

    {
        const int b = t >> 3, j8 = t & 7;
        const float4* xs = (const float4*)(x + ((size_t)b * R_ + r0 + j8) * 16);
        const float4 A = xs[0], Bv = xs[1], Cv = xs[2], Dv = xs[3];
        half8 lo, hi;
        lo[0]=(_Float16)A.x;  lo[1]=(_Float16)A.y;  lo[2]=(_Float16)A.z;  lo[3]=(_Float16)A.w;
        lo[4]=(_Float16)Bv.x; lo[5]=(_Float16)Bv.y; lo[6]=(_Float16)Bv.z; lo[7]=(_Float16)Bv.w;
        hi[0]=(_Float16)Cv.x; hi[1]=(_Float16)Cv.y; hi[2]=(_Float16)Cv.z; hi[3]=(_Float16)Cv.w;
        hi[4]=(_Float16)Dv.x; hi[5]=(_Float16)Dv.y; hi[6]=(_Float16)Dv.z; hi[7]=(_Float16)Dv.w;
        *(half8*)&tl[j8][b][0] = lo;
        *(half8*)&tl[j8][b][8] = hi;
    }
    __syncthreads();
    {
        const int rl = t >> 6, q = t & 63;
        _Float16* dst = xa + (size_t)(r0 + rl) * 1024 + q * 16;
        *(half8*)dst       = *(const half8*)&tl[rl][q][0];
        *(half8*)(dst + 8) = *(const half8*)&tl[rl][q][8];
    }
}

// ------------------------------------------------------------- MFMA pass
// D = mfma(A=Wfrag, B=xfrag): D[row=(c,o)][col=b_loc].
// lane: col b_loc = lane&31; rows (regs): R(e,h) = (e&3)+8*(e>>2)+4*h.
// wave wv owns N-tile wv: c = 2*wv+(l31>>4), o = l31&15, k = 8h+e.
// XCD-pairing: xcd = D%8; s = D/8; chunk = (s>>1)*8+xcd; bh = s&1.
// FIRST: fused W f32 fragment gather per r (no in-loop barriers), MFMA,
// stores frag to wp (bh==0). Non-FIRST: 2-r batched loop, barriers halved.
template<bool FIRST>
__global__ __launch_bounds__(1024, 4)
void caps_mfma(const _Float16* __restrict__ xa, const float* __restrict__ Wg,
               _Float16* __restrict__ wp, const float* __restrict__ vsumT,
               float* __restrict__ sdst)
{
    __shared__ _Float16 xalds[RB * 512];      // 36 KB
    __shared__ float tc_lds[2][32][33];       // logits -> (in-place) couplings

    const int D     = blockIdx.x;
    const int xcd   = D & 7;
    const int slot  = D >> 3;
    const int chunk = (slot >> 1) * 8 + xcd;  // 0..127
    const int bh    = slot & 1;

    const int tid  = threadIdx.x;
    const int lane = tid & 63;
    const int wv   = tid >> 6;                // 0..15 = N-tile
    const int h    = lane >> 5;
    const int l31  = lane & 31;
    const int r0   = chunk * RB;
    const int bg   = bh * 32 + l31;

    // stage x tile (coalesced; involution swizzle validated round 6)
    {
        const int slx = (lane << 4) ^ (((lane >> 3) & 7) << 4);
        for (int t = wv; t < RB; t += 16) {
            const char* src = (const char*)xa + (size_t)(r0 + t) * 2048 + bh * 1024 + slx;
            gload_lds16(src, (char*)xalds + t * 1024);
        }
    }

    f32x16 sacc, zf;
#pragma unroll
    for (int k = 0; k < 16; ++k) { sacc[k] = 0.f; zf[k] = 0.f; }

    half2v vh[8];
    if (!FIRST) {
#pragma unroll
        for (int e = 0; e < 16; ++e) {
            const int g = wv * 32 + (e & 3) + 8 * (e >> 2) + 4 * h;
            vh[e >> 1][e & 1] = (_Float16)vsumT[(size_t)g * 64 + bg];
        }
    }

    asm volatile("s_waitcnt vmcnt(0)" ::: "memory");
    __syncthreads();

    const int avoff = ((l31 << 5) + (h << 4)) ^ (((l31 >> 2) & 7) << 4);

    // W-fragment addressing (identical indices to the validated wprep)
    const int c_ = 2 * wv + (l31 >> 4);
    const int o_ = l31 & 15;
#define WGATHER(dst, r)                                                           \
    do {                                                                          \
        const float* ws_ = Wg + (((size_t)(r) * 32 + c_) * 16 + 8 * h) * 16 + o_; \
        _Pragma("unroll")                                                         \
        for (int e_ = 0; e_ < 8; ++e_) dst[e_] = (_Float16)ws_[e_ * 16];          \
    } while (0)

    const size_t wstride = 16 * 64 * 8;       // f16 per r

    if (FIRST) {
        half8 bc;
        WGATHER(bc, r0);
#pragma unroll 1
        for (int t = 0; t < RB; ++t) {
            const half8 av = *(const half8*)((const char*)xalds + t * 1024 + avoff);
            sacc = __builtin_amdgcn_mfma_f32_32x32x16_f16(bc, av, sacc, 0, 0, 0);
            if (bh == 0)
                *(half8*)(wp + (((size_t)(r0 + t) * 16 + wv) * 64 + lane) * 8) = bc;
            if (t + 1 < RB) WGATHER(bc, r0 + t + 1);
        }
    } else {
        const _Float16* wpb = wp + ((size_t)wv * 64 + lane) * 8;
        half8 bc0 = *(const half8*)(wpb + (size_t)(r0    ) * wstride);
        half8 bc1 = *(const half8*)(wpb + (size_t)(r0 + 1) * wstride);

#pragma unroll 1
        for (int t = 0; t < RB; t += 2) {
            const half8 av0 = *(const half8*)((const char*)xalds + (t    ) * 1024 + avoff);
            const half8 av1 = *(const half8*)((const char*)xalds + (t + 1) * 1024 + avoff);

            const f32x16 u0 = __builtin_amdgcn_mfma_f32_32x32x16_f16(bc0, av0, zf, 0, 0, 0);
            const f32x16 u1 = __builtin_amdgcn_mfma_f32_32x32x16_f16(bc1, av1, zf, 0, 0, 0);

            // prefetch next pair's W-frags (clamped tail reload harmless)
            const int tn = (t + 2 < RB) ? (t + 2) : t;
            bc0 = *(const half8*)(wpb + (size_t)(r0 + tn    ) * wstride);
            bc1 = *(const half8*)(wpb + (size_t)(r0 + tn + 1) * wstride);

            // ---- logits for BOTH r: in-register o-reduce + half-swap fold
            {
                float a0 = 0.f, a1 = 0.f, b0 = 0.f, b1 = 0.f;
#pragma unroll
                for (int e2 = 0; e2 < 4; ++e2) {
                    a0 += u0[2 * e2]         * (float)vh[e2][0];
                    a0 += u0[2 * e2 + 1]     * (float)vh[e2][1];
                    a1 += u0[8 + 2 * e2]     * (float)vh[4 + e2][0];
                    a1 += u0[8 + 2 * e2 + 1] * (float)vh[4 + e2][1];
                    b0 += u1[2 * e2]         * (float)vh[e2][0];
                    b0 += u1[2 * e2 + 1]     * (float)vh[e2][1];
                    b1 += u1[8 + 2 * e2]     * (float)vh[4 + e2][0];
                    b1 += u1[8 + 2 * e2 + 1] * (float)vh[4 + e2][1];
                }
                a0 += __shfl_xor(a0, 32);
                a1 += __shfl_xor(a1, 32);
                b0 += __shfl_xor(b0, 32);
                b1 += __shfl_xor(b1, 32);
                if (h == 0) {
                    tc_lds[0][2 * wv    ][l31] = a0;
                    tc_lds[0][2 * wv + 1][l31] = a1;
                    tc_lds[1][2 * wv    ][l31] = b0;
                    tc_lds[1][2 * wv + 1][l31] = b1;
                }
            }
            __syncthreads();

            // ---- softmax over c, all 1024 threads: (rr, c-pair a_, b2);
            // in-place (each entry read+written by exactly one thread)
            {
                const int rr   = tid >> 9;
                const int tid5 = tid & 511;
                const int a_   = tid5 & 15;
                const int b2   = tid5 >> 4;
                const float tA = tc_lds[rr][2 * a_][b2];
                const float tB = tc_lds[rr][2 * a_ + 1][b2];
                float m = fmaxf(tA, tB);
                m = fmaxf(m, __shfl_xor(m, 1));
                m = fmaxf(m, __shfl_xor(m, 2));
                m = fmaxf(m, __shfl_xor(m, 4));
                m = fmaxf(m, __shfl_xor(m, 8));
                const float eA = __expf(tA - m);
                const float eB = __expf(tB - m);
                float zs = eA + eB;
                zs += __shfl_xor(zs, 1);
                zs += __shfl_xor(zs, 2);
                zs += __shfl_xor(zs, 4);
                zs += __shfl_xor(zs, 8);
                const float inv = 1.0f / zs;
                tc_lds[rr][2 * a_][b2]     = eA * inv;
                tc_lds[rr][2 * a_ + 1][b2] = eB * inv;
            }
            __syncthreads();

            // ---- accumulate both r: sacc += c_ij * u
            {
                const float c00 = tc_lds[0][2 * wv    ][l31];
                const float c01 = tc_lds[0][2 * wv + 1][l31];
                const float c10 = tc_lds[1][2 * wv    ][l31];
                const float c11 = tc_lds[1][2 * wv + 1][l31];
#pragma unroll
                for (int e = 0; e < 8; ++e)
                    sacc[e] += c00 * u0[e] + c10 * u1[e];
#pragma unroll
                for (int e = 8; e < 16; ++e)
                    sacc[e] += c01 * u0[e] + c11 * u1[e];
            }
        }
    }
#undef WGATHER

    // epilogue: transposed partial store sT[g][b] (coalesced over b)
    const float scale = FIRST ? 0.03125f : 1.0f;
    float* sp = sdst + ((size_t)chunk << 15);
#pragma unroll
    for (int e = 0; e < 16; ++e) {
        const int g = wv * 32 + (e & 3) + 8 * (e >> 2) + 4 * h;
        sp[(size_t)g * 64 + bg] = sacc[e] * scale;
    }
}

// ------------------------------------------------- reductions + squash
// stage 1: 128 partials -> 8 (elementwise)
__global__ __launch_bounds__(256)
void caps_reduce1(const float* __restrict__ sp, float* __restrict__ s2)
{
    const int e  = blockIdx.x * 256 + threadIdx.x;
    const int pg = blockIdx.y;
    const float* p0 = sp + (size_t)pg * 16 * SELEM + e;
    float a = 0.0f;
#pragma unroll 8
    for (int p = 0; p < 16; ++p) a += p0[(size_t)p * SELEM];
    s2[pg * SELEM + e] = a;
}

// stage 2: thread owns (c,b), o in registers -> shuffle-free squash.
// mode 0: vsumT = v; 1: vsumT += v; 2: out[b][c][o] = v.
__global__ __launch_bounds__(64)
void caps_reduce2T(const float* __restrict__ src, float* __restrict__ vsumT,
                   float* __restrict__ out, int mode)
{
    const int c = blockIdx.x;
    const int b = threadIdx.x;
    float a[16];
#pragma unroll
    for (int o = 0; o < 16; ++o) a[o] = 0.0f;
    for (int p = 0; p < 8; ++p)
#pragma unroll
        for (int o = 0; o < 16; ++o)
            a[o] += src[(size_t)p * SELEM + c * 1024 + o * 64 + b];
    float sq = 0.0f;
#pragma unroll
    for (int o = 0; o < 16; ++o) sq += a[o] * a[o];
    const float n  = sqrtf(sq);
    const float sc = sq / (1.0f + sq) / (n + 1e-8f);
    if (mode == 2) {
#pragma unroll
        for (int o = 0; o < 16; ++o)
            out[(size_t)b * 512 + c * 16 + o] = a[o] * sc;
    } else if (mode == 0) {
#pragma unroll
        for (int o = 0; o < 16; ++o)
            vsumT[c * 1024 + o * 64 + b] = a[o] * sc;
    } else {
#pragma unroll
        for (int o = 0; o < 16; ++o)
            vsumT[c * 1024 + o * 64 + b] += a[o] * sc;
    }
}

// old-layout reduce2 (tier-3 fallback only)
__global__ __launch_bounds__(256)
void caps_reduce2(const float* __restrict__ src, int P,
                  float* __restrict__ vsum, float* __restrict__ out, int mode)
{
    const int e = blockIdx.x * 256 + threadIdx.x;
    float a = 0.0f;
    for (int p = 0; p < P; ++p) a += src[(size_t)p * SELEM + e];
    float sq = a * a;
#pragma unroll
    for (int off = 8; off >= 1; off >>= 1) sq += __shfl_xor(sq, off);
    const float n = sqrtf(sq);
    const float v = a * (sq / (1.0f + sq) / (n + 1e-8f));
    if (mode == 0)      vsum[e] = v;
    else if (mode == 1) vsum[e] += v;
    else                out[e] = v;
}

// ------------------------------------- tier-3 fallback: fp32 VALU path
template<bool FIRST>
__global__ __launch_bounds__(1024, 4)
void caps_pass_f32(const float* __restrict__ x, const float* __restrict__ W,
                   const float* __restrict__ vsumg, float* __restrict__ sdst)
{
    __shared__ float wlds[2][8192];
    const int tid = threadIdx.x, lane = tid & 63;
    const int c = tid & 31, dh = (tid >> 5) & 1, w = tid >> 6;
    const int r0 = blockIdx.x * RB, b0 = w << 2;
    const int key = (c & 7) << 4;
    const int cb  = (c << 10) + (dh << 5);

    float sacc[4][8];
#pragma unroll
    for (int q = 0; q < 4; ++q)
#pragma unroll
        for (int k = 0; k < 8; ++k) sacc[q][k] = 0.0f;

    float vreg[4][8];
    if (!FIRST) {
#pragma unroll
        for (int q = 0; q < 4; ++q) {
            const float4* vp = (const float4*)(vsumg + ((((b0+q) << 5) + c) << 4) + (dh << 3));
            float4 a = vp[0], bq = vp[1];
            vreg[q][0]=a.x; vreg[q][1]=a.y; vreg[q][2]=a.z; vreg[q][3]=a.w;
            vreg[q][4]=bq.x; vreg[q][5]=bq.y; vreg[q][6]=bq.z; vreg[q][7]=bq.w;
        }
    }

    const int Dloc0 = (w << 11);
    const int lx0 = (lane << 4) ^ ((((w << 1))     & 7) << 4);
    const int lx1 = (lane << 4) ^ ((((w << 1) | 1) & 7) << 4);
    const int wu = __builtin_amdgcn_readfirstlane(w);
    const float* xw = x + (size_t)((wu << 2) * R_ + r0) * 16;

#define STAGE(buf, r)                                                              \
    do {                                                                           \
        const char* wr_ = (const char*)W + ((size_t)(r) << 15);                    \
        gload_lds16(wr_ + Dloc0        + lx0, (char*)wlds[buf] + Dloc0);           \
        gload_lds16(wr_ + Dloc0 + 1024 + lx1, (char*)wlds[buf] + Dloc0 + 1024);    \
    } while (0)

    STAGE(0, r0);
#pragma unroll 1
    for (int t = 0; t < RB; ++t) {
        const int cur = t & 1;
        if (t + 1 < RB) { STAGE(cur ^ 1, r0 + t + 1); asm volatile("s_waitcnt vmcnt(2)" ::: "memory"); }
        else            { asm volatile("s_waitcnt vmcnt(0)" ::: "memory"); }
        __builtin_amdgcn_s_barrier();
        __builtin_amdgcn_sched_barrier(0);

        const char* lb = (const char*)wlds[cur];
        float u[4][8];
#pragma unroll
        for (int q = 0; q < 4; ++q)
#pragma unroll
            for (int k = 0; k < 8; ++k) u[q][k] = 0.0f;

#pragma unroll
        for (int i = 0; i < 16; ++i) {
            const int A = (cb + (i << 6)) ^ key;
            float4 w0 = *(const float4*)(lb + A);
            float4 w1 = *(const float4*)(lb + (A ^ 16));
            float wv[8] = {w0.x, w0.y, w0.z, w0.w, w1.x, w1.y, w1.z, w1.w};
#pragma unroll
            for (int q = 0; q < 4; ++q) {
                const float xv = xw[(size_t)q * (R_ * 16) + t * 16 + i];
#pragma unroll
                for (int k = 0; k < 8; ++k) u[q][k] = fmaf(xv, wv[k], u[q][k]);
            }
        }

#pragma unroll
        for (int q = 0; q < 4; ++q) {
            float cij;
            if (FIRST) cij = 0.03125f;
            else {
                float th = 0.0f;
#pragma unroll
                for (int k = 0; k < 8; ++k) th = fmaf(u[q][k], vreg[q][k], th);
                th += __shfl_xor(th, 32);
                float m = th;
#pragma unroll
                for (int off = 16; off >= 1; off >>= 1) m = fmaxf(m, __shfl_xor(m, off));
                const float e = __expf(th - m);
                float ssum = e;
#pragma unroll
                for (int off = 16; off >= 1; off >>= 1) ssum += __shfl_xor(ssum, off);
                cij = e / ssum;
            }
#pragma unroll
            for (int k = 0; k < 8; ++k) sacc[q][k] = fmaf(cij, u[q][k], sacc[q][k]);
        }
        __builtin_amdgcn_s_barrier();
    }
#undef STAGE

#pragma unroll
    for (int q = 0; q < 4; ++q) {
        float* sp = sdst + ((((b0+q) << 5) + c) << 4) + (dh << 3);
#pragma unroll
        for (int k = 0; k < 8; ++k) atomicAdd(sp + k, sacc[q][k]);
    }
}

// ---------------------------------------------------------------- launcher
extern "C" void kernel_launch(void* const* d_in, const int* in_sizes, int n_in,
                              void* d_out, int out_size, void* d_ws, size_t ws_size,
                              hipStream_t stream)
{
    const float* x = (const float*)d_in[0];          // [64, 4608, 16]
    const float* W = (const float*)d_in[1];          // [4608, 32, 16, 16]
    float* out = (float*)d_out;                      // [64, 32, 16]

    const size_t WPB = (size_t)R_ * 16 * 64 * 8 * sizeof(_Float16);  // 75,497,472
    const size_t XAB = (size_t)R_ * 64 * 16 * sizeof(_Float16);      //  9,437,184
    const size_t SPB = (size_t)NBLK * SELEM * sizeof(float);         // 16,777,216
    const size_t S2B = (size_t)8 * SELEM * sizeof(float);
    const size_t VSB = (size_t)SELEM * sizeof(float);
    char* wsc = (char*)d_ws;

    if (ws_size >= WPB + XAB + SPB + S2B + VSB) {
        _Float16* wp  = (_Float16*)wsc;
        _Float16* xa  = (_Float16*)(wsc + WPB);
        float* s_part = (float*)(wsc + WPB + XAB);
        float* s2     = (float*)(wsc + WPB + XAB + SPB);
        float* vsumT  = (float*)(wsc + WPB + XAB + SPB + S2B);

        caps_prep<<<576, 512, 0, stream>>>(x, xa);

        caps_mfma<true ><<<256, 1024, 0, stream>>>(xa, W, wp, nullptr, s_part);
        caps_reduce1<<<dim3(128, 8), 256, 0, stream>>>(s_part, s2);
        caps_reduce2T<<<32, 64, 0, stream>>>(s2, vsumT, nullptr, 0);

        caps_mfma<false><<<256, 1024, 0, stream>>>(xa, W, wp, vsumT, s_part);
        caps_reduce1<<<dim3(128, 8), 256, 0, stream>>>(s_part, s2);
        caps_reduce2T<<<32, 64, 0, stream>>>(s2, vsumT, nullptr, 1);

        caps_mfma<false><<<256, 1024, 0, stream>>>(xa, W, wp, vsumT, s_part);
        caps_reduce1<<<dim3(128, 8), 256, 0, stream>>>(s_part, s2);
        caps_reduce2T<<<32, 64, 0, stream>>>(s2, vsumT, out, 2);
    } else {
        // tiny-ws fallback: fp32 VALU path (atomic accumulate, old layout)
        float* s    = (float*)wsc;
        float* vsum = s + SELEM;

        hipMemsetAsync(s, 0, VSB, stream);
        caps_pass_f32<true><<<NBLK, 1024, 0, stream>>>(x, W, nullptr, s);
        caps_reduce2<<<128, 256, 0, stream>>>(s, 1, vsum, nullptr, 0);

        hipMemsetAsync(s, 0, VSB, stream);
        caps_pass_f32<false><<<NBLK, 1024, 0, stream>>>(x, W, vsum, s);
        caps_reduce2<<<128, 256, 0, stream>>>(s, 1, vsum, nullptr, 1);

        hipMemsetAsync(s, 0, VSB, stream);
        caps_pass_f32<false><<<NBLK, 1024, 0, stream>>>(x, W, vsum, s);
        caps_reduce2<<<128, 256, 0, stream>>>(s, 1, nullptr, out, 2);
    }
}